// Round 9
// baseline (212.534 us; speedup 1.0000x reference)
//
#include <hip/hip_runtime.h>

#define D 128
#define NB 64               // histogram/scatter blocks per type
#define MAXNW8 12544        // packed 8-bit words: 4*12544 = 50176 bins >= N (LDS 49 KB)

typedef short short8 __attribute__((ext_vector_type(8)));
typedef float f32x4 __attribute__((ext_vector_type(4)));

static __device__ __forceinline__ unsigned short f2bf(float f) {
    unsigned int u = __float_as_uint(f);
    unsigned int r = (u + 0x7FFFu + ((u >> 16) & 1u)) >> 16;
    return (unsigned short)r;
}
static __device__ __forceinline__ float bflo(unsigned int w) {
    return __uint_as_float(w << 16);
}
static __device__ __forceinline__ float bfhi(unsigned int w) {
    return __uint_as_float(w & 0xffff0000u);
}
static __device__ __forceinline__ unsigned int pk2bf(float lo, float hi) {
    return (unsigned int)f2bf(lo) | ((unsigned int)f2bf(hi) << 16);
}

// ---------------- S1: fused front-end: zone A = 8-bit histograms (one pass),
//                     zone B = x->bf16, zone C = weight fold ----------------
__global__ __launch_bounds__(1024) void k_stage1(
    const int* __restrict__ src, const int* __restrict__ dst,
    unsigned int* __restrict__ hist, int E, int NW8, int nHist,
    const float* __restrict__ x, unsigned short* __restrict__ xh, long long total4, int nX4,
    const float* __restrict__ Wc, const float* __restrict__ Wa,
    const float* __restrict__ bc, const float* __restrict__ ba,
    unsigned short* __restrict__ Wt, float* __restrict__ beff) {
    __shared__ unsigned int h8[MAXNW8];
    int t = threadIdx.x;
    int bx = blockIdx.x;

    if (bx < nHist) {
        // ---- zone A: row bx = (type*NB + b). 8-bit packed counts, full range. ----
        int b = bx & (NB - 1);
        int type = bx >> 6;
        const int* __restrict__ ids = type ? dst : src;
        for (int i = t; i < NW8; i += 1024) h8[i] = 0;
        __syncthreads();
        int slice = (E + NB - 1) / NB;
        int beg = b * slice;
        int end = beg + slice; if (end > E) end = E;
        for (int e = beg + t; e < end; e += 1024) {
            int v = ids[e];
            atomicAdd(&h8[v >> 2], 1u << ((v & 3) * 8));
        }
        __syncthreads();
        unsigned int* outp = hist + (size_t)bx * NW8;
        for (int i = t; i < NW8; i += 1024) outp[i] = h8[i];
    } else if (bx < nHist + nX4) {
        // ---- zone B: x -> bf16 ----
        long long i = (long long)(bx - nHist) * 1024 + t;
        if (i < total4) {
            float4 v = *(const float4*)&x[i * 4];
            ushort4 o;
            o.x = f2bf(v.x); o.y = f2bf(v.y); o.z = f2bf(v.z); o.w = f2bf(v.w);
            *(ushort4*)&xh[i * 4] = o;
        }
    } else {
        // ---- zone C: Wt[j*256+k] = k<128 ? (Wc@Wa_top)[k][j] : Wa[k][j]; beff ----
        int cidx = bx - nHist - nX4;
        if (cidx < 32) {
            int o = cidx * 1024 + t;
            int k = o >> 7;
            int j = o & 127;
            float acc;
            if (k < 128) {
                acc = 0.f;
                for (int l = 0; l < 128; l++) acc += Wc[k * 128 + l] * Wa[l * 128 + j];
            } else {
                acc = Wa[k * 128 + j];
            }
            Wt[(size_t)j * 256 + k] = f2bf(acc);
        } else if (t < 128) {
            float acc = ba[t];
            for (int k = 0; k < 128; k++) acc += bc[k] * Wa[k * 128 + t];
            beff[t] = acc;
        }
    }
}

// ---------------- S2: merged hreduce + scan (decoupled lookback over partials) ----
// Each block owns 1024 nodes (256 thr x 4 nodes/word). Computes norms, rewrites
// src-hist rows as 8-bit per-block dst prefixes, then produces offsets[] directly.
// partial[] must be zeroed before launch (flag bit 31 = ready).
__global__ __launch_bounds__(256) void k_hredscan(unsigned int* __restrict__ hist,
                                                  float* __restrict__ norm_out,
                                                  float* __restrict__ norm_in,
                                                  unsigned int* __restrict__ partial,
                                                  int* __restrict__ offsets,
                                                  int N, int NW8, int nblocks) {
    __shared__ int red[256];
    int t = threadIdx.x;
    int bx = blockIdx.x;
    int w = bx * 256 + t;

    unsigned int p0 = 0, p1 = 0, p2 = 0, p3 = 0;
    if (w < NW8) {
        unsigned int d0 = 0, d1 = 0, d2 = 0, d3 = 0;
        for (int b = 0; b < NB; b++) {
            unsigned int v = hist[(size_t)b * NW8 + w];
            d0 += v & 0xffu; d1 += (v >> 8) & 0xffu; d2 += (v >> 16) & 0xffu; d3 += v >> 24;
        }
        for (int b = 0; b < NB; b++) {
            unsigned int v = hist[(size_t)(NB + b) * NW8 + w];
            hist[(size_t)b * NW8 + w] = p0 | (p1 << 8) | (p2 << 16) | (p3 << 24);
            p0 += v & 0xffu; p1 += (v >> 8) & 0xffu; p2 += (v >> 16) & 0xffu; p3 += v >> 24;
        }
        int n = 4 * w;
        unsigned int dd[4] = {d0, d1, d2, d3};
        unsigned int pp[4] = {p0, p1, p2, p3};
        for (int i = 0; i < 4; i++) {
            if (n + i < N) {
                norm_out[n + i] = rsqrtf((float)(dd[i] > 1 ? dd[i] : 1));
                norm_in[n + i]  = rsqrtf((float)(pp[i] > 1 ? pp[i] : 1));
            }
        }
        if (n + 1 >= N) p1 = 0;
        if (n + 2 >= N) p2 = 0;
        if (n + 3 >= N) p3 = 0;
    }
    int s = (int)(p0 + p1 + p2 + p3);

    // block total -> publish
    red[t] = s;
    __syncthreads();
    for (int off = 128; off > 0; off >>= 1) {
        if (t < off) red[t] += red[t + off];
        __syncthreads();
    }
    if (t == 0)
        __hip_atomic_store(&partial[bx], (unsigned int)red[0] | 0x80000000u,
                           __ATOMIC_RELEASE, __HIP_MEMORY_SCOPE_AGENT);

    // lookback: thread t spins on partial[t] for t < bx
    unsigned int pv = 0;
    if (t < bx) {
        unsigned int v;
        do {
            v = __hip_atomic_load(&partial[t], __ATOMIC_ACQUIRE, __HIP_MEMORY_SCOPE_AGENT);
        } while (!(v & 0x80000000u));
        pv = v & 0x7fffffffu;
    }
    __syncthreads();
    red[t] = (int)pv;
    __syncthreads();
    for (int off = 128; off > 0; off >>= 1) {
        if (t < off) red[t] += red[t + off];
        __syncthreads();
    }
    int base = red[0];
    __syncthreads();

    // inclusive scan of per-thread sums
    red[t] = s;
    __syncthreads();
    for (int off = 1; off < 256; off <<= 1) {
        int a = (t >= off) ? red[t - off] : 0;
        __syncthreads();
        red[t] += a;
        __syncthreads();
    }
    int run = red[t] - s + base;
    int n = 4 * w;
    unsigned int pp[4] = {p0, p1, p2, p3};
    for (int i = 0; i < 4; i++) {
        if (n + i < N) offsets[n + i] = run;
        run += (int)pp[i];
    }
    if (bx == nblocks - 1 && t == 255) offsets[N] = base + red[255];
}

// ---------------- S3: counting-sort scatter — one pass, no global atomics ----------------
__global__ __launch_bounds__(1024) void k_scatter(const int* __restrict__ src,
                                                  const int* __restrict__ dst,
                                                  const int* __restrict__ offsets,
                                                  const unsigned int* __restrict__ prefix,
                                                  int* __restrict__ edge_src,
                                                  int E, int NW8) {
    __shared__ unsigned int h8[MAXNW8];
    int t = threadIdx.x;
    int b = blockIdx.x;
    for (int i = t; i < NW8; i += 1024) h8[i] = 0;
    __syncthreads();
    int slice = (E + NB - 1) / NB;
    int beg = b * slice;
    int end = beg + slice; if (end > E) end = E;
    const unsigned int* __restrict__ prow = prefix + (size_t)b * NW8;
    for (int e = beg + t; e < end; e += 1024) {
        int d = dst[e];
        int sh = (d & 3) * 8;
        unsigned int old = atomicAdd(&h8[d >> 2], 1u << sh);
        int rank = (int)((old >> sh) & 0xffu);
        int base = offsets[d] + (int)((prow[d >> 2] >> sh) & 0xffu);
        edge_src[base + rank] = src[e];
    }
}

// ---------------- S4: CSR aggregation: full-wave rows, unroll-8 in flight ----------------
__global__ __launch_bounds__(256) void k_aggr(const unsigned short* __restrict__ xh,
                                              const int* __restrict__ edge_src,
                                              const int* __restrict__ offsets,
                                              const float* __restrict__ norm_out,
                                              const float* __restrict__ norm_in,
                                              unsigned short* __restrict__ yh, int N) {
    int node = blockIdx.x * 4 + (threadIdx.x >> 6);
    int lane = threadIdx.x & 63;
    if (node >= N) return;
    int beg = offsets[node];
    int end = offsets[node + 1];
    float nd = norm_in[node];
    float ax = 0.f, ay = 0.f;

    for (int jb = beg; jb < end; jb += 64) {
        int cnt = end - jb; if (cnt > 64) cnt = 64;
        int eidx = 0; float nsv = 0.f;
        if (lane < cnt) {
            eidx = edge_src[jb + lane];     // one coalesced batch load
            nsv  = norm_out[eidx];          // 64 gathers in flight
        }
        int k = 0;
        for (; k + 8 <= cnt; k += 8) {
#pragma unroll
            for (int u = 0; u < 8; u++) {   // 8 independent 256B row loads in flight
                int s = __shfl(eidx, k + u);
                float ns = __shfl(nsv, k + u);
                unsigned int v = *(const unsigned int*)&xh[(size_t)s * D + lane * 2];
                ax += bflo(v) * ns;
                ay += bfhi(v) * ns;
            }
        }
        for (; k < cnt; k++) {
            int s = __shfl(eidx, k);
            float ns = __shfl(nsv, k);
            unsigned int v = *(const unsigned int*)&xh[(size_t)s * D + lane * 2];
            ax += bflo(v) * ns;
            ay += bfhi(v) * ns;
        }
    }

    *(unsigned int*)&yh[(size_t)node * D + lane * 2] = pk2bf(ax * nd, ay * nd);
}

// ---------------- S5: MFMA GEMM: out = [yh | xh] @ W + beff ----------------
#define WT_STRIDE 136
__global__ __launch_bounds__(256) void k_gemm(const unsigned short* __restrict__ yh,
                                              const unsigned short* __restrict__ xh,
                                              const unsigned short* __restrict__ Wt,
                                              const float* __restrict__ beff,
                                              float* __restrict__ out, int N) {
    __shared__ unsigned short Bs[128 * WT_STRIDE];

    int t = threadIdx.x;
    int w = t >> 6;
    int lane = t & 63;
    int m = lane & 15;
    int q = lane >> 4;
    int row0 = blockIdx.x * 64;
    int arow = row0 + w * 16 + m;
    bool arow_ok = arow < N;

    f32x4 acc[8];
#pragma unroll
    for (int ct = 0; ct < 8; ct++) acc[ct] = (f32x4){0.f, 0.f, 0.f, 0.f};

    for (int kh = 0; kh < 2; kh++) {
#pragma unroll
        for (int i = 0; i < 8; i++) {
            int idx = t + i * 256;
            int rr = idx >> 4;
            int cc = (idx & 15) * 8;
            *(short8*)&Bs[rr * WT_STRIDE + cc] =
                *(const short8*)&Wt[(size_t)rr * 256 + kh * 128 + cc];
        }
        __syncthreads();

        const unsigned short* Abase = (kh == 0) ? yh : xh;
        const unsigned short* arowp = Abase + (size_t)arow * D;

#pragma unroll
        for (int kk = 0; kk < 4; kk++) {
            short8 a = (short8){0,0,0,0,0,0,0,0};
            if (arow_ok) a = *(const short8*)&arowp[kk * 32 + q * 8];
#pragma unroll
            for (int ct = 0; ct < 8; ct++) {
                short8 b = *(const short8*)&Bs[(ct * 16 + m) * WT_STRIDE + kk * 32 + q * 8];
                acc[ct] = __builtin_amdgcn_mfma_f32_16x16x32_bf16(a, b, acc[ct], 0, 0, 0);
            }
        }
        __syncthreads();
    }

#pragma unroll
    for (int ct = 0; ct < 8; ct++) {
        int col = ct * 16 + m;
        float bv = beff[col];
#pragma unroll
        for (int j = 0; j < 4; j++) {
            int r = row0 + w * 16 + q * 4 + j;
            if (r < N) out[(size_t)r * D + col] = acc[ct][j] + bv;
        }
    }
}

static size_t align256(size_t v) { return (v + 255) & ~(size_t)255; }

extern "C" void kernel_launch(void* const* d_in, const int* in_sizes, int n_in,
                              void* d_out, int out_size, void* d_ws, size_t ws_size,
                              hipStream_t stream) {
    const float* x     = (const float*)d_in[0];
    const int*   src   = (const int*)d_in[1];
    const int*   dst   = (const int*)d_in[2];
    const float* Wconv = (const float*)d_in[3];
    const float* bconv = (const float*)d_in[4];
    const float* Waggr = (const float*)d_in[5];
    const float* baggr = (const float*)d_in[6];
    float* out = (float*)d_out;

    int N = in_sizes[0] / D;
    int E = in_sizes[1];
    int NW8 = (N + 3) / 4;              // packed 8-bit words per histogram row
    int nbh = (NW8 + 255) / 256;        // hredscan blocks (1024 nodes each)
    int nHist = NB * 2;
    long long total4 = (long long)N * D / 4;
    int nX4 = (int)((total4 + 1023) / 1024);

    char* p = (char*)d_ws;
    // hist: [src half: NB rows][dst half: NB rows] of NW8 words each. After
    // k_hredscan the src half holds 8-bit per-block dst prefixes; the dst half
    // is dead -> edge_src overlays it (NB*NW8*4 = N bytes >= E*4? E*4=3.2MB, NB*NW8*4=3.2MB).
    unsigned int* hist = (unsigned int*)p;
    int* edge_src = (int*)(hist + (size_t)NB * NW8);
    size_t dstHalf = (size_t)NB * NW8 * 4;
    size_t edgeBytes = (size_t)E * 4;
    p += align256((size_t)NB * NW8 * 4 + (edgeBytes > dstHalf ? edgeBytes : dstHalf));
    int* offsets = (int*)p;      p += align256((size_t)(N + 1) * sizeof(int));
    unsigned int* partial = (unsigned int*)p; p += align256((size_t)(nbh + 1) * sizeof(unsigned int));
    float* norm_out = (float*)p; p += align256((size_t)N * sizeof(float));
    float* norm_in  = (float*)p; p += align256((size_t)N * sizeof(float));
    float* beff  = (float*)p;    p += align256(128 * sizeof(float));
    unsigned short* xh  = (unsigned short*)p; p += align256((size_t)N * D * 2);
    unsigned short* yh  = (unsigned short*)p; p += align256((size_t)N * D * 2);
    unsigned short* Wt  = (unsigned short*)p; p += align256(256 * 128 * 2);

    hipMemsetAsync(partial, 0, (size_t)(nbh + 1) * sizeof(unsigned int), stream);

    k_stage1<<<nHist + nX4 + 33, 1024, 0, stream>>>(
        src, dst, hist, E, NW8, nHist,
        x, xh, total4, nX4,
        Wconv, Waggr, bconv, baggr, Wt, beff);
    k_hredscan<<<nbh, 256, 0, stream>>>(hist, norm_out, norm_in, partial, offsets, N, NW8, nbh);
    k_scatter<<<NB, 1024, 0, stream>>>(src, dst, offsets, hist, edge_src, E, NW8);
    k_aggr<<<(N + 3) / 4, 256, 0, stream>>>(xh, edge_src, offsets, norm_out, norm_in, yh, N);
    k_gemm<<<(N + 63) / 64, 256, 0, stream>>>(yh, xh, Wt, beff, out, N);
}

// Round 10
// 208.839 us; speedup vs baseline: 1.0177x; 1.0177x over previous
//
#include <hip/hip_runtime.h>

#define D 128
#define NB 128              // histogram/scatter blocks per type
#define MAXNW8 12544        // packed 8-bit words: 4*12544 = 50176 bins >= N (LDS 49 KB)

typedef short short8 __attribute__((ext_vector_type(8)));
typedef float f32x4 __attribute__((ext_vector_type(4)));

static __device__ __forceinline__ unsigned short f2bf(float f) {
    unsigned int u = __float_as_uint(f);
    unsigned int r = (u + 0x7FFFu + ((u >> 16) & 1u)) >> 16;
    return (unsigned short)r;
}
static __device__ __forceinline__ float bflo(unsigned int w) {
    return __uint_as_float(w << 16);
}
static __device__ __forceinline__ float bfhi(unsigned int w) {
    return __uint_as_float(w & 0xffff0000u);
}
static __device__ __forceinline__ unsigned int pk2bf(float lo, float hi) {
    return (unsigned int)f2bf(lo) | ((unsigned int)f2bf(hi) << 16);
}

// ---------------- S1: fused front-end: zone A = 8-bit histograms (one pass),
//                     zone B = x->bf16, zone C = weight fold + partial zeroing ----------------
__global__ __launch_bounds__(1024) void k_stage1(
    const int* __restrict__ src, const int* __restrict__ dst,
    unsigned int* __restrict__ hist, int E, int NW8, int nHist,
    const float* __restrict__ x, unsigned short* __restrict__ xh, long long total4, int nX4,
    const float* __restrict__ Wc, const float* __restrict__ Wa,
    const float* __restrict__ bc, const float* __restrict__ ba,
    unsigned short* __restrict__ Wt, float* __restrict__ beff,
    unsigned int* __restrict__ partial, int nbh) {
    __shared__ unsigned int h8[MAXNW8];
    int t = threadIdx.x;
    int bx = blockIdx.x;

    if (bx < nHist) {
        // ---- zone A: row bx = (type*NB + b). 8-bit packed counts, full range, one pass. ----
        int b = bx % NB;
        int type = bx / NB;
        const int* __restrict__ ids = type ? dst : src;
        for (int i = t; i < NW8; i += 1024) h8[i] = 0;
        __syncthreads();
        int slice = (E + NB - 1) / NB;
        int beg = b * slice;
        int end = beg + slice; if (end > E) end = E;
        for (int e = beg + t; e < end; e += 1024) {
            int v = ids[e];
            atomicAdd(&h8[v >> 2], 1u << ((v & 3) * 8));
        }
        __syncthreads();
        unsigned int* outp = hist + (size_t)bx * NW8;
        for (int i = t; i < NW8; i += 1024) outp[i] = h8[i];
    } else if (bx < nHist + nX4) {
        // ---- zone B: x -> bf16 ----
        long long i = (long long)(bx - nHist) * 1024 + t;
        if (i < total4) {
            float4 v = *(const float4*)&x[i * 4];
            ushort4 o;
            o.x = f2bf(v.x); o.y = f2bf(v.y); o.z = f2bf(v.z); o.w = f2bf(v.w);
            *(ushort4*)&xh[i * 4] = o;
        }
    } else {
        // ---- zone C: Wt[j*256+k] = k<128 ? (Wc@Wa_top)[k][j] : Wa[k][j]; beff; zero partial ----
        int cidx = bx - nHist - nX4;
        if (cidx < 32) {
            int o = cidx * 1024 + t;
            int k = o >> 7;
            int j = o & 127;
            float acc;
            if (k < 128) {
                acc = 0.f;
                for (int l = 0; l < 128; l++) acc += Wc[k * 128 + l] * Wa[l * 128 + j];
            } else {
                acc = Wa[k * 128 + j];
            }
            Wt[(size_t)j * 256 + k] = f2bf(acc);
        } else {
            if (t < 128) {
                float acc = ba[t];
                for (int k = 0; k < 128; k++) acc += bc[k] * Wa[k * 128 + t];
                beff[t] = acc;
            } else if (t - 128 <= nbh) {
                partial[t - 128] = 0;   // lookback flags cleared here (no extra memset dispatch)
            }
        }
    }
}

// ---------------- S2: merged hreduce + scan (decoupled lookback over partials) ----
// Each block owns 1024 nodes (256 thr x 4 nodes/word). Computes norms, rewrites
// src-hist rows as 8-bit per-block dst prefixes, then produces offsets[] directly.
__global__ __launch_bounds__(256) void k_hredscan(unsigned int* __restrict__ hist,
                                                  float* __restrict__ norm_out,
                                                  float* __restrict__ norm_in,
                                                  unsigned int* __restrict__ partial,
                                                  int* __restrict__ offsets,
                                                  int N, int NW8, int nblocks) {
    __shared__ int red[256];
    int t = threadIdx.x;
    int bx = blockIdx.x;
    int w = bx * 256 + t;

    unsigned int p0 = 0, p1 = 0, p2 = 0, p3 = 0;
    if (w < NW8) {
        unsigned int d0 = 0, d1 = 0, d2 = 0, d3 = 0;
        for (int b = 0; b < NB; b++) {
            unsigned int v = hist[(size_t)b * NW8 + w];
            d0 += v & 0xffu; d1 += (v >> 8) & 0xffu; d2 += (v >> 16) & 0xffu; d3 += v >> 24;
        }
        for (int b = 0; b < NB; b++) {
            unsigned int v = hist[(size_t)(NB + b) * NW8 + w];
            hist[(size_t)b * NW8 + w] = p0 | (p1 << 8) | (p2 << 16) | (p3 << 24);
            p0 += v & 0xffu; p1 += (v >> 8) & 0xffu; p2 += (v >> 16) & 0xffu; p3 += v >> 24;
        }
        int n = 4 * w;
        unsigned int dd[4] = {d0, d1, d2, d3};
        unsigned int pp[4] = {p0, p1, p2, p3};
        for (int i = 0; i < 4; i++) {
            if (n + i < N) {
                norm_out[n + i] = rsqrtf((float)(dd[i] > 1 ? dd[i] : 1));
                norm_in[n + i]  = rsqrtf((float)(pp[i] > 1 ? pp[i] : 1));
            }
        }
        if (n + 1 >= N) p1 = 0;
        if (n + 2 >= N) p2 = 0;
        if (n + 3 >= N) p3 = 0;
    }
    int s = (int)(p0 + p1 + p2 + p3);

    // block total -> publish
    red[t] = s;
    __syncthreads();
    for (int off = 128; off > 0; off >>= 1) {
        if (t < off) red[t] += red[t + off];
        __syncthreads();
    }
    if (t == 0)
        __hip_atomic_store(&partial[bx], (unsigned int)red[0] | 0x80000000u,
                           __ATOMIC_RELEASE, __HIP_MEMORY_SCOPE_AGENT);

    // lookback: thread t spins on partial[t] for t < bx
    unsigned int pv = 0;
    if (t < bx) {
        unsigned int v;
        do {
            v = __hip_atomic_load(&partial[t], __ATOMIC_ACQUIRE, __HIP_MEMORY_SCOPE_AGENT);
        } while (!(v & 0x80000000u));
        pv = v & 0x7fffffffu;
    }
    __syncthreads();
    red[t] = (int)pv;
    __syncthreads();
    for (int off = 128; off > 0; off >>= 1) {
        if (t < off) red[t] += red[t + off];
        __syncthreads();
    }
    int base = red[0];
    __syncthreads();

    // inclusive scan of per-thread sums
    red[t] = s;
    __syncthreads();
    for (int off = 1; off < 256; off <<= 1) {
        int a = (t >= off) ? red[t - off] : 0;
        __syncthreads();
        red[t] += a;
        __syncthreads();
    }
    int run = red[t] - s + base;
    int n = 4 * w;
    unsigned int pp[4] = {p0, p1, p2, p3};
    for (int i = 0; i < 4; i++) {
        if (n + i < N) offsets[n + i] = run;
        run += (int)pp[i];
    }
    if (bx == nblocks - 1 && t == 255) offsets[N] = base + red[255];
}

// ---------------- S3: counting-sort scatter — one pass, no global atomics ----------------
__global__ __launch_bounds__(1024) void k_scatter(const int* __restrict__ src,
                                                  const int* __restrict__ dst,
                                                  const int* __restrict__ offsets,
                                                  const unsigned int* __restrict__ prefix,
                                                  int* __restrict__ edge_src,
                                                  int E, int NW8) {
    __shared__ unsigned int h8[MAXNW8];
    int t = threadIdx.x;
    int b = blockIdx.x;
    for (int i = t; i < NW8; i += 1024) h8[i] = 0;
    __syncthreads();
    int slice = (E + NB - 1) / NB;
    int beg = b * slice;
    int end = beg + slice; if (end > E) end = E;
    const unsigned int* __restrict__ prow = prefix + (size_t)b * NW8;
    for (int e = beg + t; e < end; e += 1024) {
        int d = dst[e];
        int sh = (d & 3) * 8;
        unsigned int old = atomicAdd(&h8[d >> 2], 1u << sh);
        int rank = (int)((old >> sh) & 0xffu);
        int base = offsets[d] + (int)((prow[d >> 2] >> sh) & 0xffu);
        edge_src[base + rank] = src[e];
    }
}

// ---------------- S4: CSR aggregation: full-wave rows, unroll-8 in flight ----------------
__global__ __launch_bounds__(256) void k_aggr(const unsigned short* __restrict__ xh,
                                              const int* __restrict__ edge_src,
                                              const int* __restrict__ offsets,
                                              const float* __restrict__ norm_out,
                                              const float* __restrict__ norm_in,
                                              unsigned short* __restrict__ yh, int N) {
    int node = blockIdx.x * 4 + (threadIdx.x >> 6);
    int lane = threadIdx.x & 63;
    if (node >= N) return;
    int beg = offsets[node];
    int end = offsets[node + 1];
    float nd = norm_in[node];
    float ax = 0.f, ay = 0.f;

    for (int jb = beg; jb < end; jb += 64) {
        int cnt = end - jb; if (cnt > 64) cnt = 64;
        int eidx = 0; float nsv = 0.f;
        if (lane < cnt) {
            eidx = edge_src[jb + lane];     // one coalesced batch load
            nsv  = norm_out[eidx];          // 64 gathers in flight
        }
        int k = 0;
        for (; k + 8 <= cnt; k += 8) {
#pragma unroll
            for (int u = 0; u < 8; u++) {   // 8 independent 256B row loads in flight
                int s = __shfl(eidx, k + u);
                float ns = __shfl(nsv, k + u);
                unsigned int v = *(const unsigned int*)&xh[(size_t)s * D + lane * 2];
                ax += bflo(v) * ns;
                ay += bfhi(v) * ns;
            }
        }
        for (; k < cnt; k++) {
            int s = __shfl(eidx, k);
            float ns = __shfl(nsv, k);
            unsigned int v = *(const unsigned int*)&xh[(size_t)s * D + lane * 2];
            ax += bflo(v) * ns;
            ay += bfhi(v) * ns;
        }
    }

    *(unsigned int*)&yh[(size_t)node * D + lane * 2] = pk2bf(ax * nd, ay * nd);
}

// ---------------- S5: MFMA GEMM: out = [yh | xh] @ W + beff ----------------
#define WT_STRIDE 136
__global__ __launch_bounds__(256) void k_gemm(const unsigned short* __restrict__ yh,
                                              const unsigned short* __restrict__ xh,
                                              const unsigned short* __restrict__ Wt,
                                              const float* __restrict__ beff,
                                              float* __restrict__ out, int N) {
    __shared__ unsigned short Bs[128 * WT_STRIDE];

    int t = threadIdx.x;
    int w = t >> 6;
    int lane = t & 63;
    int m = lane & 15;
    int q = lane >> 4;
    int row0 = blockIdx.x * 64;
    int arow = row0 + w * 16 + m;
    bool arow_ok = arow < N;

    f32x4 acc[8];
#pragma unroll
    for (int ct = 0; ct < 8; ct++) acc[ct] = (f32x4){0.f, 0.f, 0.f, 0.f};

    for (int kh = 0; kh < 2; kh++) {
#pragma unroll
        for (int i = 0; i < 8; i++) {
            int idx = t + i * 256;
            int rr = idx >> 4;
            int cc = (idx & 15) * 8;
            *(short8*)&Bs[rr * WT_STRIDE + cc] =
                *(const short8*)&Wt[(size_t)rr * 256 + kh * 128 + cc];
        }
        __syncthreads();

        const unsigned short* Abase = (kh == 0) ? yh : xh;
        const unsigned short* arowp = Abase + (size_t)arow * D;

#pragma unroll
        for (int kk = 0; kk < 4; kk++) {
            short8 a = (short8){0,0,0,0,0,0,0,0};
            if (arow_ok) a = *(const short8*)&arowp[kk * 32 + q * 8];
#pragma unroll
            for (int ct = 0; ct < 8; ct++) {
                short8 b = *(const short8*)&Bs[(ct * 16 + m) * WT_STRIDE + kk * 32 + q * 8];
                acc[ct] = __builtin_amdgcn_mfma_f32_16x16x32_bf16(a, b, acc[ct], 0, 0, 0);
            }
        }
        __syncthreads();
    }

#pragma unroll
    for (int ct = 0; ct < 8; ct++) {
        int col = ct * 16 + m;
        float bv = beff[col];
#pragma unroll
        for (int j = 0; j < 4; j++) {
            int r = row0 + w * 16 + q * 4 + j;
            if (r < N) out[(size_t)r * D + col] = acc[ct][j] + bv;
        }
    }
}

static size_t align256(size_t v) { return (v + 255) & ~(size_t)255; }

extern "C" void kernel_launch(void* const* d_in, const int* in_sizes, int n_in,
                              void* d_out, int out_size, void* d_ws, size_t ws_size,
                              hipStream_t stream) {
    const float* x     = (const float*)d_in[0];
    const int*   src   = (const int*)d_in[1];
    const int*   dst   = (const int*)d_in[2];
    const float* Wconv = (const float*)d_in[3];
    const float* bconv = (const float*)d_in[4];
    const float* Waggr = (const float*)d_in[5];
    const float* baggr = (const float*)d_in[6];
    float* out = (float*)d_out;

    int N = in_sizes[0] / D;
    int E = in_sizes[1];
    int NW8 = (N + 3) / 4;              // packed 8-bit words per histogram row
    int nbh = (NW8 + 255) / 256;        // hredscan blocks (1024 nodes each)
    int nHist = NB * 2;
    long long total4 = (long long)N * D / 4;
    int nX4 = (int)((total4 + 1023) / 1024);

    char* p = (char*)d_ws;
    // hist: [src half: NB rows][dst half: NB rows] of NW8 words each. After
    // k_hredscan the src half holds 8-bit per-block dst prefixes; the dst half
    // is dead -> edge_src overlays it (NB*NW8*4 = 6.4MB >= E*4 = 3.2MB).
    unsigned int* hist = (unsigned int*)p;
    int* edge_src = (int*)(hist + (size_t)NB * NW8);
    size_t dstHalf = (size_t)NB * NW8 * 4;
    size_t edgeBytes = (size_t)E * 4;
    p += align256((size_t)NB * NW8 * 4 + (edgeBytes > dstHalf ? edgeBytes : dstHalf));
    int* offsets = (int*)p;      p += align256((size_t)(N + 1) * sizeof(int));
    unsigned int* partial = (unsigned int*)p; p += align256((size_t)(nbh + 1) * sizeof(unsigned int));
    float* norm_out = (float*)p; p += align256((size_t)N * sizeof(float));
    float* norm_in  = (float*)p; p += align256((size_t)N * sizeof(float));
    float* beff  = (float*)p;    p += align256(128 * sizeof(float));
    unsigned short* xh  = (unsigned short*)p; p += align256((size_t)N * D * 2);
    unsigned short* yh  = (unsigned short*)p; p += align256((size_t)N * D * 2);
    unsigned short* Wt  = (unsigned short*)p; p += align256(256 * 128 * 2);

    k_stage1<<<nHist + nX4 + 33, 1024, 0, stream>>>(
        src, dst, hist, E, NW8, nHist,
        x, xh, total4, nX4,
        Wconv, Waggr, bconv, baggr, Wt, beff,
        partial, nbh);
    k_hredscan<<<nbh, 256, 0, stream>>>(hist, norm_out, norm_in, partial, offsets, N, NW8, nbh);
    k_scatter<<<NB, 1024, 0, stream>>>(src, dst, offsets, hist, edge_src, E, NW8);
    k_aggr<<<(N + 3) / 4, 256, 0, stream>>>(xh, edge_src, offsets, norm_out, norm_in, yh, N);
    k_gemm<<<(N + 63) / 64, 256, 0, stream>>>(yh, xh, Wt, beff, out, N);
}

// Round 11
// 194.912 us; speedup vs baseline: 1.0904x; 1.0715x over previous
//
#include <hip/hip_runtime.h>

#define D 128
#define NB 64              // histogram/scatter blocks per type
#define RBITS 15           // node-range split: 32768 bins per range
#define RSIZE (1 << RBITS)
#define RWORDS (RSIZE / 2) // 16384 packed words = 64 KB LDS

typedef short short8 __attribute__((ext_vector_type(8)));
typedef float f32x4 __attribute__((ext_vector_type(4)));
typedef float f32x2 __attribute__((ext_vector_type(2)));

static __device__ __forceinline__ unsigned short f2bf(float f) {
    unsigned int u = __float_as_uint(f);
    unsigned int r = (u + 0x7FFFu + ((u >> 16) & 1u)) >> 16;
    return (unsigned short)r;
}
static __device__ __forceinline__ unsigned int pk2bf(float lo, float hi) {
    return (unsigned int)f2bf(lo) | ((unsigned int)f2bf(hi) << 16);
}

// ---------------- S1: fused front-end: zone A = histograms, zone B = x->bf16 + x->fp8,
//                     zone C = weight fold ----------------
__global__ __launch_bounds__(1024) void k_stage1(
    const int* __restrict__ src, const int* __restrict__ dst,
    unsigned int* __restrict__ hist, int E, int NW, int nHist,
    const float* __restrict__ x, unsigned short* __restrict__ xh,
    unsigned int* __restrict__ xs8, long long total4, int nX4,
    const float* __restrict__ Wc, const float* __restrict__ Wa,
    const float* __restrict__ bc, const float* __restrict__ ba,
    unsigned short* __restrict__ Wt, float* __restrict__ beff) {
    __shared__ unsigned int h[RWORDS];
    int t = threadIdx.x;
    int bx = blockIdx.x;

    if (bx < nHist) {
        // ---- zone A: per-block packed 16-bit histograms (LDS atomics only) ----
        int b = bx % NB;
        int type = (bx / NB) & 1;
        int z = bx / (NB * 2);
        const int* __restrict__ ids = type ? dst : src;
        for (int i = t; i < RWORDS; i += 1024) h[i] = 0;
        __syncthreads();
        int slice = (E + NB - 1) / NB;
        int beg = b * slice;
        int end = beg + slice; if (end > E) end = E;
        for (int e = beg + t; e < end; e += 1024) {
            int v = ids[e];
            if ((v >> RBITS) != z) continue;
            int lv = v & (RSIZE - 1);
            atomicAdd(&h[lv >> 1], 1u << ((lv & 1) * 16));
        }
        __syncthreads();
        unsigned int* outp = hist + (size_t)(type * NB + b) * NW;
        int wbeg = z * RWORDS;
        int wend = wbeg + RWORDS; if (wend > NW) wend = NW;
        for (int i = wbeg + t; i < wend; i += 1024) outp[i] = h[i - wbeg];
    } else if (bx < nHist + nX4) {
        // ---- zone B: x -> bf16 (for GEMM) and x -> fp8 e4m3 (for gather) ----
        long long i = (long long)(bx - nHist) * 1024 + t;
        if (i < total4) {
            float4 v = *(const float4*)&x[i * 4];
            ushort4 o;
            o.x = f2bf(v.x); o.y = f2bf(v.y); o.z = f2bf(v.z); o.w = f2bf(v.w);
            *(ushort4*)&xh[i * 4] = o;
            unsigned int p8 = __builtin_amdgcn_cvt_pk_fp8_f32(v.x, v.y, 0u, false);
            p8 = __builtin_amdgcn_cvt_pk_fp8_f32(v.z, v.w, p8, true);
            xs8[i] = p8;
        }
    } else {
        // ---- zone C: Wt[j*256+k] = k<128 ? (Wc@Wa_top)[k][j] : Wa[k][j]; beff ----
        int cidx = bx - nHist - nX4;
        if (cidx < 32) {
            int o = cidx * 1024 + t;
            int k = o >> 7;
            int j = o & 127;
            float acc;
            if (k < 128) {
                acc = 0.f;
                for (int l = 0; l < 128; l++) acc += Wc[k * 128 + l] * Wa[l * 128 + j];
            } else {
                acc = Wa[k * 128 + j];
            }
            Wt[(size_t)j * 256 + k] = f2bf(acc);
        } else if (t < 128) {
            float acc = ba[t];
            for (int k = 0; k < 128; k++) acc += bc[k] * Wa[k * 128 + t];
            beff[t] = acc;
        }
    }
}

// ---------------- S2: reduce hists -> deg/norms; rewrite src-hist as dst prefixes;
//                     emit per-block partial sums ----------------
__global__ __launch_bounds__(256) void k_hreduce(unsigned int* __restrict__ hist,
                                                 int* __restrict__ deg_in,
                                                 float* __restrict__ norm_out,
                                                 float* __restrict__ norm_in,
                                                 int* __restrict__ partial,
                                                 int N, int NW) {
    __shared__ int red[256];
    int t = threadIdx.x;
    int w = blockIdx.x * 256 + t;
    unsigned int p0 = 0, p1 = 0;
    if (w < NW) {
        unsigned int do0 = 0, do1 = 0;
        for (int b = 0; b < NB; b++) {
            unsigned int v = hist[(size_t)b * NW + w];
            do0 += v & 0xffffu; do1 += v >> 16;
        }
        for (int b = 0; b < NB; b++) {
            unsigned int v = hist[(size_t)(NB + b) * NW + w];
            hist[(size_t)b * NW + w] = p0 | (p1 << 16);  // thread-exclusive word: no race
            p0 += v & 0xffffu; p1 += v >> 16;
        }
        int n0 = 2 * w, n1 = 2 * w + 1;
        deg_in[n0]   = (int)p0;
        norm_out[n0] = rsqrtf((float)(do0 > 1 ? do0 : 1));
        norm_in[n0]  = rsqrtf((float)(p0 > 1 ? p0 : 1));
        if (n1 < N) {
            deg_in[n1]   = (int)p1;
            norm_out[n1] = rsqrtf((float)(do1 > 1 ? do1 : 1));
            norm_in[n1]  = rsqrtf((float)(p1 > 1 ? p1 : 1));
        } else {
            p1 = 0;
        }
    }
    red[t] = (int)(p0 + p1);
    __syncthreads();
    for (int off = 128; off > 0; off >>= 1) {
        if (t < off) red[t] += red[t + off];
        __syncthreads();
    }
    if (t == 0) partial[blockIdx.x] = red[0];
}

// ---------------- S3: scan with self-computed block prefix (512 nodes/block) ----------------
__global__ __launch_bounds__(256) void k_scan3(const int* __restrict__ deg,
                                               const int* __restrict__ partial,
                                               int* __restrict__ offsets, int N) {
    __shared__ int red[256];
    int t = threadIdx.x;
    int bx = blockIdx.x;
    // block prefix over partials (gridDim.x <= 256)
    int pv = (t < bx) ? partial[t] : 0;
    red[t] = pv;
    __syncthreads();
    for (int off = 128; off > 0; off >>= 1) {
        if (t < off) red[t] += red[t + off];
        __syncthreads();
    }
    int base = red[0];
    __syncthreads();

    int nb2 = bx * 512 + t * 2;
    int v0 = (nb2 < N) ? deg[nb2] : 0;
    int v1 = (nb2 + 1 < N) ? deg[nb2 + 1] : 0;
    int s = v0 + v1;
    red[t] = s;
    __syncthreads();
    for (int off = 1; off < 256; off <<= 1) {
        int a = (t >= off) ? red[t - off] : 0;
        __syncthreads();
        red[t] += a;
        __syncthreads();
    }
    int excl = red[t] - s + base;
    if (nb2 < N)     offsets[nb2] = excl;
    if (nb2 + 1 < N) offsets[nb2 + 1] = excl + v0;
    if (bx == gridDim.x - 1 && t == 255) offsets[N] = base + red[255];
}

// ---------------- S4: counting-sort scatter — no global atomics ----------------
__global__ __launch_bounds__(1024) void k_scatter(const int* __restrict__ src,
                                                  const int* __restrict__ dst,
                                                  const int* __restrict__ offsets,
                                                  const unsigned int* __restrict__ prefix,
                                                  int* __restrict__ edge_src,
                                                  int E, int NW) {
    __shared__ unsigned int h[RWORDS];
    int t = threadIdx.x;
    int b = blockIdx.x;
    int z = blockIdx.y;
    for (int i = t; i < RWORDS; i += 1024) h[i] = 0;
    __syncthreads();
    int slice = (E + NB - 1) / NB;
    int beg = b * slice;
    int end = beg + slice; if (end > E) end = E;
    const unsigned int* __restrict__ prow = prefix + (size_t)b * NW;
    for (int e = beg + t; e < end; e += 1024) {
        int d = dst[e];
        if ((d >> RBITS) != z) continue;
        int lv = d & (RSIZE - 1);
        int sh = (lv & 1) * 16;
        unsigned int old = atomicAdd(&h[lv >> 1], 1u << sh);
        int rank = (int)((old >> sh) & 0xffffu);
        int base = offsets[d] + (int)((prow[d >> 1] >> sh) & 0xffffu);
        edge_src[base + rank] = src[e];
    }
}

// ---------------- S5: CSR aggregation over fp8 rows: 16 rows in flight per wave ----------------
// wave = 2 groups x 32 lanes; each group reads one 128B fp8 row (4B/lane), hw-decodes.
__global__ __launch_bounds__(256) void k_aggr(const unsigned int* __restrict__ xs8,
                                              const int* __restrict__ edge_src,
                                              const int* __restrict__ offsets,
                                              const float* __restrict__ norm_out,
                                              const float* __restrict__ norm_in,
                                              unsigned short* __restrict__ yh, int N) {
    int node = blockIdx.x * 4 + (threadIdx.x >> 6);
    int lane = threadIdx.x & 63;
    if (node >= N) return;
    int g = lane >> 5;       // group 0/1
    int li = lane & 31;      // lane-in-group: elems li*4 .. li*4+3
    int beg = offsets[node];
    int end = offsets[node + 1];
    float nd = norm_in[node];
    float acc[4] = {0.f, 0.f, 0.f, 0.f};

    for (int jb = beg; jb < end; jb += 64) {
        int cnt = end - jb; if (cnt > 64) cnt = 64;
        int eidx = 0; float nsv = 0.f;
        if (lane < cnt) {
            eidx = edge_src[jb + lane];     // one coalesced batch load
            nsv  = norm_out[eidx];          // 64 norm gathers in flight
        }
        int k = 0;
        for (; k + 16 <= cnt; k += 16) {
#pragma unroll
            for (int u = 0; u < 16; u += 2) {   // 16 rows in flight across both groups
                int kg = k + u + g;
                int s = __shfl(eidx, kg);
                float ns = __shfl(nsv, kg);
                unsigned int v = xs8[(size_t)s * 32 + li];   // 32 words per 128-elem row
                f32x2 lo = __builtin_amdgcn_cvt_pk_f32_fp8(v, false);
                f32x2 hi = __builtin_amdgcn_cvt_pk_f32_fp8(v, true);
                acc[0] += lo[0] * ns;
                acc[1] += lo[1] * ns;
                acc[2] += hi[0] * ns;
                acc[3] += hi[1] * ns;
            }
        }
        for (; k < cnt; k += 2) {
            int kg = k + g;
            if (kg < cnt) {
                int s = __shfl(eidx, kg);
                float ns = __shfl(nsv, kg);
                unsigned int v = xs8[(size_t)s * 32 + li];
                f32x2 lo = __builtin_amdgcn_cvt_pk_f32_fp8(v, false);
                f32x2 hi = __builtin_amdgcn_cvt_pk_f32_fp8(v, true);
                acc[0] += lo[0] * ns;
                acc[1] += lo[1] * ns;
                acc[2] += hi[0] * ns;
                acc[3] += hi[1] * ns;
            }
        }
    }

    // combine the 2 groups (butterfly over lane bit 5)
#pragma unroll
    for (int i = 0; i < 4; i++) acc[i] += __shfl_xor(acc[i], 32);

    if (g == 0) {
        uint2 o;
        o.x = pk2bf(acc[0] * nd, acc[1] * nd);
        o.y = pk2bf(acc[2] * nd, acc[3] * nd);
        *(uint2*)&yh[(size_t)node * D + li * 4] = o;
    }
}

// ---------------- S6: MFMA GEMM: out = [yh | xh] @ W + beff ----------------
#define WT_STRIDE 136
__global__ __launch_bounds__(256) void k_gemm(const unsigned short* __restrict__ yh,
                                              const unsigned short* __restrict__ xh,
                                              const unsigned short* __restrict__ Wt,
                                              const float* __restrict__ beff,
                                              float* __restrict__ out, int N) {
    __shared__ unsigned short Bs[128 * WT_STRIDE];

    int t = threadIdx.x;
    int w = t >> 6;
    int lane = t & 63;
    int m = lane & 15;
    int q = lane >> 4;
    int row0 = blockIdx.x * 64;
    int arow = row0 + w * 16 + m;
    bool arow_ok = arow < N;

    f32x4 acc[8];
#pragma unroll
    for (int ct = 0; ct < 8; ct++) acc[ct] = (f32x4){0.f, 0.f, 0.f, 0.f};

    for (int kh = 0; kh < 2; kh++) {
#pragma unroll
        for (int i = 0; i < 8; i++) {
            int idx = t + i * 256;
            int rr = idx >> 4;
            int cc = (idx & 15) * 8;
            *(short8*)&Bs[rr * WT_STRIDE + cc] =
                *(const short8*)&Wt[(size_t)rr * 256 + kh * 128 + cc];
        }
        __syncthreads();

        const unsigned short* Abase = (kh == 0) ? yh : xh;
        const unsigned short* arowp = Abase + (size_t)arow * D;

#pragma unroll
        for (int kk = 0; kk < 4; kk++) {
            short8 a = (short8){0,0,0,0,0,0,0,0};
            if (arow_ok) a = *(const short8*)&arowp[kk * 32 + q * 8];
#pragma unroll
            for (int ct = 0; ct < 8; ct++) {
                short8 b = *(const short8*)&Bs[(ct * 16 + m) * WT_STRIDE + kk * 32 + q * 8];
                acc[ct] = __builtin_amdgcn_mfma_f32_16x16x32_bf16(a, b, acc[ct], 0, 0, 0);
            }
        }
        __syncthreads();
    }

#pragma unroll
    for (int ct = 0; ct < 8; ct++) {
        int col = ct * 16 + m;
        float bv = beff[col];
#pragma unroll
        for (int j = 0; j < 4; j++) {
            int r = row0 + w * 16 + q * 4 + j;
            if (r < N) out[(size_t)r * D + col] = acc[ct][j] + bv;
        }
    }
}

static size_t align256(size_t v) { return (v + 255) & ~(size_t)255; }

extern "C" void kernel_launch(void* const* d_in, const int* in_sizes, int n_in,
                              void* d_out, int out_size, void* d_ws, size_t ws_size,
                              hipStream_t stream) {
    const float* x     = (const float*)d_in[0];
    const int*   src   = (const int*)d_in[1];
    const int*   dst   = (const int*)d_in[2];
    const float* Wconv = (const float*)d_in[3];
    const float* bconv = (const float*)d_in[4];
    const float* Waggr = (const float*)d_in[5];
    const float* baggr = (const float*)d_in[6];
    float* out = (float*)d_out;

    int N = in_sizes[0] / D;
    int E = in_sizes[1];
    int NW = (N + 1) / 2;               // packed 16-bit words per histogram row
    int RS = (N + RSIZE - 1) / RSIZE;   // node-range splits
    int nbh = (NW + 255) / 256;         // hreduce/scan blocks (512 nodes each)
    int nHist = NB * 2 * RS;
    long long total4 = (long long)N * D / 4;
    int nX4 = (int)((total4 + 1023) / 1024);

    char* p = (char*)d_ws;
    // hist: [src half: NB rows][dst half: NB rows]; after k_hreduce the src half
    // holds per-block dst prefixes and the dst half is dead -> edge_src overlays it.
    unsigned int* hist = (unsigned int*)p;
    int* edge_src = (int*)(hist + (size_t)NB * NW);
    size_t dstHalf = (size_t)NB * NW * 4;
    size_t edgeBytes = (size_t)E * 4;
    p += align256((size_t)NB * NW * 4 + (edgeBytes > dstHalf ? edgeBytes : dstHalf));
    int* deg_in  = (int*)p;      p += align256((size_t)N * sizeof(int));
    int* offsets = (int*)p;      p += align256((size_t)(N + 1) * sizeof(int));
    int* partial = (int*)p;      p += align256((size_t)(nbh + 1) * sizeof(int));
    float* norm_out = (float*)p; p += align256((size_t)N * sizeof(float));
    float* norm_in  = (float*)p; p += align256((size_t)N * sizeof(float));
    float* beff  = (float*)p;    p += align256(128 * sizeof(float));
    unsigned short* xh  = (unsigned short*)p; p += align256((size_t)N * D * 2);
    unsigned short* yh  = (unsigned short*)p; p += align256((size_t)N * D * 2);
    unsigned int* xs8   = (unsigned int*)p;   p += align256((size_t)N * D);
    unsigned short* Wt  = (unsigned short*)p; p += align256(256 * 128 * 2);

    k_stage1<<<nHist + nX4 + 33, 1024, 0, stream>>>(
        src, dst, hist, E, NW, nHist,
        x, xh, xs8, total4, nX4,
        Wconv, Waggr, bconv, baggr, Wt, beff);
    k_hreduce<<<nbh, 256, 0, stream>>>(hist, deg_in, norm_out, norm_in, partial, N, NW);
    k_scan3<<<nbh, 256, 0, stream>>>(deg_in, partial, offsets, N);
    k_scatter<<<dim3(NB, RS), 1024, 0, stream>>>(src, dst, offsets, hist, edge_src, E, NW);
    k_aggr<<<(N + 3) / 4, 256, 0, stream>>>(xs8, edge_src, offsets, norm_out, norm_in, yh, N);
    k_gemm<<<(N + 63) / 64, 256, 0, stream>>>(yh, xh, Wt, beff, out, N);
}